// Round 1
// baseline (562.256 us; speedup 1.0000x reference)
//
#include <hip/hip_runtime.h>
#include <math.h>

#define D 96
#define NPB 8

__device__ __forceinline__ unsigned mapf(float f){
  unsigned u = __float_as_uint(f);
  return (u & 0x80000000u) ? ~u : (u | 0x80000000u);
}
__device__ __forceinline__ float unmapf(unsigned m){
  unsigned u = (m & 0x80000000u) ? (m ^ 0x80000000u) : ~m;
  return __uint_as_float(u);
}
__device__ __forceinline__ int lbound(const int* __restrict__ a, int n, int v){
  int lo = 0, hi = n;
  while (lo < hi){ int mid = (lo + hi) >> 1; if (a[mid] < v) lo = mid + 1; else hi = mid; }
  return lo;
}

// K1: node transforms. acc = x@w1+b1 ; x2o/x3o/x4o = x@w{2,3,4}+b{2,3,4}
__global__ __launch_bounds__(96) void k_transform(
    const float* __restrict__ x,
    const float* __restrict__ w1, const float* __restrict__ b1,
    const float* __restrict__ w2, const float* __restrict__ b2,
    const float* __restrict__ w3, const float* __restrict__ b3,
    const float* __restrict__ w4, const float* __restrict__ b4,
    float* __restrict__ acc, float* __restrict__ x2o,
    float* __restrict__ x3o, float* __restrict__ x4o, int n){
  __shared__ float xs[NPB][D];
  int d = threadIdx.x;
  int n0 = blockIdx.x * NPB;
  #pragma unroll
  for (int i = 0; i < NPB; ++i){
    int r = n0 + i;
    xs[i][d] = (r < n) ? x[(size_t)r * D + d] : 0.0f;
  }
  __syncthreads();
  float a1[NPB] = {0}, a2[NPB] = {0}, a3[NPB] = {0}, a4[NPB] = {0};
  for (int k = 0; k < D; ++k){
    float v1 = w1[k * D + d], v2 = w2[k * D + d], v3 = w3[k * D + d], v4 = w4[k * D + d];
    #pragma unroll
    for (int i = 0; i < NPB; ++i){
      float xv = xs[i][k];
      a1[i] += xv * v1; a2[i] += xv * v2; a3[i] += xv * v3; a4[i] += xv * v4;
    }
  }
  float bb1 = b1[d], bb2 = b2[d], bb3 = b3[d], bb4 = b4[d];
  #pragma unroll
  for (int i = 0; i < NPB; ++i){
    int r = n0 + i;
    if (r < n){
      size_t o = (size_t)r * D + d;
      acc[o] = a1[i] + bb1;
      x2o[o] = a2[i] + bb2;
      x3o[o] = a3[i] + bb3;
      x4o[o] = a4[i] + bb4;
    }
  }
}

// K1b: per-node scalars p5 = dot(x3, w5row), pb = dot(x3, w5b). One wave per node.
__global__ __launch_bounds__(256) void k_p5(
    const float* __restrict__ x3, const float* __restrict__ w5,
    const float* __restrict__ w5b, float* __restrict__ p5,
    float* __restrict__ pb, int n){
  int node = blockIdx.x * 4 + (threadIdx.x >> 6);
  int lane = threadIdx.x & 63;
  if (node >= n) return;
  const float* row = x3 + (size_t)node * D;
  float v0 = row[lane];
  float s5 = v0 * w5[lane];
  float sb = v0 * w5b[lane];
  if (lane < 32){
    float v1 = row[64 + lane];
    s5 += v1 * w5[64 + lane];
    sb += v1 * w5b[64 + lane];
  }
  #pragma unroll
  for (int off = 32; off > 0; off >>= 1){
    s5 += __shfl_down(s5, off);
    sb += __shfl_down(sb, off);
  }
  if (lane == 0){ p5[node] = s5; pb[node] = sb; }
}

// K2: edge scores + atomic segment-max (mapped uint) + degree histogram
__global__ __launch_bounds__(256) void k_scores(
    const float* __restrict__ x3, const float* __restrict__ x4,
    const float* __restrict__ eattr, const int* __restrict__ srcI,
    const int* __restrict__ dstI, const float* __restrict__ p5,
    const float* __restrict__ pb, float* __restrict__ scores,
    unsigned* __restrict__ maxMapped, int* __restrict__ deg, int E){
  int e = blockIdx.x * blockDim.x + threadIdx.x;
  if (e >= E) return;
  int s = srcI[e], t = dstI[e];
  const float4* r3 = (const float4*)(x3 + (size_t)t * D);
  const float4* r4 = (const float4*)(x4 + (size_t)s * D);
  float acc = 0.0f;
  #pragma unroll
  for (int q = 0; q < D / 4; ++q){
    float4 u = r3[q], v = r4[q];
    acc += u.x * v.x + u.y * v.y + u.z * v.z + u.w * v.w;
  }
  float a = eattr[e];
  float sc = (acc + a * p5[t] + pb[t]) * 0.10206207261596577f; // 1/sqrt(96)
  scores[e] = sc;
  atomicMax(&maxMapped[t], mapf(sc));
  atomicAdd(&deg[t], 1);
}

// K3: single-block exclusive scan deg -> rowp (wave-level shfl scan)
__global__ __launch_bounds__(1024) void k_scan(
    const int* __restrict__ deg, int* __restrict__ rowp, int n){
  __shared__ int wsum[16];
  int tid = threadIdx.x;
  int lane = tid & 63, wid = tid >> 6;
  int running = 0;
  for (int base = 0; base < n; base += 1024){
    int i = base + tid;
    int v = (i < n) ? deg[i] : 0;
    int s = v;
    #pragma unroll
    for (int off = 1; off < 64; off <<= 1){
      int t = __shfl_up(s, off);
      if (lane >= off) s += t;
    }
    if (lane == 63) wsum[wid] = s;
    __syncthreads();
    if (tid < 16){
      int ws = wsum[tid];
      #pragma unroll
      for (int off = 1; off < 16; off <<= 1){
        int t = __shfl_up(ws, off);
        if (tid >= off) ws += t;
      }
      wsum[tid] = ws;
    }
    __syncthreads();
    int waveoff = (wid > 0) ? wsum[wid - 1] : 0;
    if (i < n) rowp[i] = running + waveoff + s - v;
    running += wsum[15];
    __syncthreads();
  }
  if (tid == 0) rowp[n] = running;
}

// K4: exp numerators + denom atomics + scatter into CSR order
__global__ __launch_bounds__(256) void k_exscatter(
    const float* __restrict__ scores, const int* __restrict__ srcI,
    const int* __restrict__ dstI, const unsigned* __restrict__ maxMapped,
    float* __restrict__ denom, const int* __restrict__ rowp,
    int* __restrict__ fill, int* __restrict__ sortedSrc,
    float* __restrict__ sortedEx, int E){
  int e = blockIdx.x * blockDim.x + threadIdx.x;
  if (e >= E) return;
  int t = dstI[e];
  float ex = expf(scores[e] - unmapf(maxMapped[t]));
  atomicAdd(&denom[t], ex);
  int pos = rowp[t] + atomicAdd(&fill[t], 1);
  sortedSrc[pos] = srcI[e];
  sortedEx[pos] = ex;
}

// K5: per-node aggregation (block per node, coalesced x2 row reads), atomic-free
__global__ __launch_bounds__(96) void k_aggregate(
    const float* __restrict__ x2, const float* __restrict__ sortedEx,
    const int* __restrict__ sortedSrc, const int* __restrict__ rowp,
    const float* __restrict__ denom, float* __restrict__ node_acc, int n){
  int nd = blockIdx.x;
  int d = threadIdx.x;
  int beg = rowp[nd], end = rowp[nd + 1];
  float inv = 1.0f / (denom[nd] + 1e-16f);
  float a = node_acc[(size_t)nd * D + d];
  int p = beg;
  for (; p + 3 < end; p += 4){
    int s0 = sortedSrc[p], s1 = sortedSrc[p + 1], s2 = sortedSrc[p + 2], s3 = sortedSrc[p + 3];
    float w0 = sortedEx[p] * inv, w1 = sortedEx[p + 1] * inv;
    float w2 = sortedEx[p + 2] * inv, w3 = sortedEx[p + 3] * inv;
    a += w0 * x2[(size_t)s0 * D + d];
    a += w1 * x2[(size_t)s1 * D + d];
    a += w2 * x2[(size_t)s2 * D + d];
    a += w3 * x2[(size_t)s3 * D + d];
  }
  for (; p < end; ++p){
    a += (sortedEx[p] * inv) * x2[(size_t)sortedSrc[p] * D + d];
  }
  node_acc[(size_t)nd * D + d] = a;
}

// K6: per-graph partial sums (batch is sorted; binary-search boundaries)
__global__ __launch_bounds__(96) void k_pool(
    const float* __restrict__ node_out, const int* __restrict__ batch,
    float* __restrict__ sums, int n){
  int g = blockIdx.x;
  int chunk = blockIdx.y, nch = gridDim.y;
  int lo = lbound(batch, n, g);
  int hi = lbound(batch, n, g + 1);
  int cnt = hi - lo;
  if (cnt <= 0) return;
  int per = (cnt + nch - 1) / nch;
  int b = lo + chunk * per;
  int e = min(b + per, hi);
  if (b >= e) return;
  int d = threadIdx.x;
  float s = 0.0f;
  for (int r = b; r < e; ++r) s += node_out[(size_t)r * D + d];
  atomicAdd(&sums[g * D + d], s);
}

// K7: divide by counts
__global__ __launch_bounds__(256) void k_final(
    const float* __restrict__ sums, const int* __restrict__ batch,
    float* __restrict__ out, int n, int total){
  int i = blockIdx.x * blockDim.x + threadIdx.x;
  if (i >= total) return;
  int g = i / D;
  int lo = lbound(batch, n, g);
  int hi = lbound(batch, n, g + 1);
  float c = (float)((hi - lo) > 1 ? (hi - lo) : 1);
  out[i] = sums[i] / c;
}

extern "C" void kernel_launch(void* const* d_in, const int* in_sizes, int n_in,
                              void* d_out, int out_size, void* d_ws, size_t ws_size,
                              hipStream_t stream){
  const float* x     = (const float*)d_in[0];
  const int*   eidx  = (const int*)d_in[1];
  const float* eattr = (const float*)d_in[2];
  const int*   batch = (const int*)d_in[3];
  const float* w1 = (const float*)d_in[4];
  const float* b1 = (const float*)d_in[5];
  const float* w2 = (const float*)d_in[6];
  const float* b2 = (const float*)d_in[7];
  const float* w3 = (const float*)d_in[8];
  const float* b3 = (const float*)d_in[9];
  const float* w4 = (const float*)d_in[10];
  const float* b4 = (const float*)d_in[11];
  const float* w5 = (const float*)d_in[12];
  const float* b5 = (const float*)d_in[13];
  float* out = (float*)d_out;

  const int N = in_sizes[0] / D;
  const int E = in_sizes[2];          // edge_attr is [E,1]
  const int* srcI = eidx;
  const int* dstI = eidx + E;

  // workspace layout
  char* base = (char*)d_ws;
  size_t off = 0;
  auto alloc = [&](size_t bytes) -> char* {
    char* p = base + off;
    off = (off + bytes + 255) & ~(size_t)255;
    return p;
  };
  // zeroed region first (one contiguous memset)
  char* zbase = base;
  int*      deg       = (int*)alloc((size_t)N * 4);
  int*      fill      = (int*)alloc((size_t)N * 4);
  float*    denom     = (float*)alloc((size_t)N * 4);
  unsigned* maxMapped = (unsigned*)alloc((size_t)N * 4);
  float*    sums      = (float*)alloc((size_t)out_size * 4);
  size_t zbytes = off;
  // rest
  float* node_acc = (float*)alloc((size_t)N * D * 4);
  float* x2v      = (float*)alloc((size_t)N * D * 4);
  float* x3v      = (float*)alloc((size_t)N * D * 4);
  float* x4v      = (float*)alloc((size_t)N * D * 4);
  float* p5       = (float*)alloc((size_t)N * 4);
  float* pb       = (float*)alloc((size_t)N * 4);
  float* scores   = (float*)alloc((size_t)E * 4);
  int*   rowp     = (int*)alloc((size_t)(N + 1) * 4);
  int*   sortedSrc= (int*)alloc((size_t)E * 4);
  float* sortedEx = (float*)alloc((size_t)E * 4);
  (void)ws_size; (void)n_in;

  hipMemsetAsync(zbase, 0, zbytes, stream);

  k_transform<<<dim3((N + NPB - 1) / NPB), dim3(D), 0, stream>>>(
      x, w1, b1, w2, b2, w3, b3, w4, b4, node_acc, x2v, x3v, x4v, N);
  k_p5<<<dim3((N + 3) / 4), dim3(256), 0, stream>>>(x3v, w5, b5, p5, pb, N);
  k_scores<<<dim3((E + 255) / 256), dim3(256), 0, stream>>>(
      x3v, x4v, eattr, srcI, dstI, p5, pb, scores, maxMapped, deg, E);
  k_scan<<<dim3(1), dim3(1024), 0, stream>>>(deg, rowp, N);
  k_exscatter<<<dim3((E + 255) / 256), dim3(256), 0, stream>>>(
      scores, srcI, dstI, maxMapped, denom, rowp, fill, sortedSrc, sortedEx, E);
  k_aggregate<<<dim3(N), dim3(D), 0, stream>>>(
      x2v, sortedEx, sortedSrc, rowp, denom, node_acc, N);
  k_pool<<<dim3(out_size / D, 32), dim3(D), 0, stream>>>(node_acc, batch, sums, N);
  k_final<<<dim3((out_size + 255) / 256), dim3(256), 0, stream>>>(
      sums, batch, out, N, out_size);
}

// Round 2
// 509.738 us; speedup vs baseline: 1.1030x; 1.1030x over previous
//
#include <hip/hip_runtime.h>
#include <math.h>

#define D 96
#define NPB 8
#define RSQ 0.10206207261596577f  // 1/sqrt(96)

__device__ __forceinline__ int lbound(const int* __restrict__ a, int n, int v){
  int lo = 0, hi = n;
  while (lo < hi){ int mid = (lo + hi) >> 1; if (a[mid] < v) lo = mid + 1; else hi = mid; }
  return lo;
}

// K1: node transforms. acc = x@w1+b1 ; x2o/x3o/x4o = x@w{2,3,4}+b{2,3,4}
__global__ __launch_bounds__(96) void k_transform(
    const float* __restrict__ x,
    const float* __restrict__ w1, const float* __restrict__ b1,
    const float* __restrict__ w2, const float* __restrict__ b2,
    const float* __restrict__ w3, const float* __restrict__ b3,
    const float* __restrict__ w4, const float* __restrict__ b4,
    float* __restrict__ acc, float* __restrict__ x2o,
    float* __restrict__ x3o, float* __restrict__ x4o, int n){
  __shared__ float xs[NPB][D];
  int d = threadIdx.x;
  int n0 = blockIdx.x * NPB;
  #pragma unroll
  for (int i = 0; i < NPB; ++i){
    int r = n0 + i;
    xs[i][d] = (r < n) ? x[(size_t)r * D + d] : 0.0f;
  }
  __syncthreads();
  float a1[NPB] = {0}, a2[NPB] = {0}, a3[NPB] = {0}, a4[NPB] = {0};
  for (int k = 0; k < D; ++k){
    float v1 = w1[k * D + d], v2 = w2[k * D + d], v3 = w3[k * D + d], v4 = w4[k * D + d];
    #pragma unroll
    for (int i = 0; i < NPB; ++i){
      float xv = xs[i][k];
      a1[i] += xv * v1; a2[i] += xv * v2; a3[i] += xv * v3; a4[i] += xv * v4;
    }
  }
  float bb1 = b1[d], bb2 = b2[d], bb3 = b3[d], bb4 = b4[d];
  #pragma unroll
  for (int i = 0; i < NPB; ++i){
    int r = n0 + i;
    if (r < n){
      size_t o = (size_t)r * D + d;
      acc[o] = a1[i] + bb1;
      x2o[o] = a2[i] + bb2;
      x3o[o] = a3[i] + bb3;
      x4o[o] = a4[i] + bb4;
    }
  }
}

// K1b: per-node scalars p5 = dot(x3, w5row), pb = dot(x3, w5b). One wave per node.
__global__ __launch_bounds__(256) void k_p5(
    const float* __restrict__ x3, const float* __restrict__ w5,
    const float* __restrict__ w5b, float* __restrict__ p5,
    float* __restrict__ pb, int n){
  int node = blockIdx.x * 4 + (threadIdx.x >> 6);
  int lane = threadIdx.x & 63;
  if (node >= n) return;
  const float* row = x3 + (size_t)node * D;
  float v0 = row[lane];
  float s5 = v0 * w5[lane];
  float sb = v0 * w5b[lane];
  if (lane < 32){
    float v1 = row[64 + lane];
    s5 += v1 * w5[64 + lane];
    sb += v1 * w5b[64 + lane];
  }
  #pragma unroll
  for (int off = 32; off > 0; off >>= 1){
    s5 += __shfl_down(s5, off);
    sb += __shfl_down(sb, off);
  }
  if (lane == 0){ p5[node] = s5; pb[node] = sb; }
}

// K2: degree histogram over dst
__global__ __launch_bounds__(256) void k_deg(
    const int* __restrict__ dstI, int* __restrict__ deg, int E){
  int e = blockIdx.x * blockDim.x + threadIdx.x;
  if (e >= E) return;
  atomicAdd(&deg[dstI[e]], 1);
}

// K3: single-block exclusive scan deg -> rowp (wave-level shfl scan)
__global__ __launch_bounds__(1024) void k_scan(
    const int* __restrict__ deg, int* __restrict__ rowp, int n){
  __shared__ int wsum[16];
  int tid = threadIdx.x;
  int lane = tid & 63, wid = tid >> 6;
  int running = 0;
  for (int base = 0; base < n; base += 1024){
    int i = base + tid;
    int v = (i < n) ? deg[i] : 0;
    int s = v;
    #pragma unroll
    for (int off = 1; off < 64; off <<= 1){
      int t = __shfl_up(s, off);
      if (lane >= off) s += t;
    }
    if (lane == 63) wsum[wid] = s;
    __syncthreads();
    if (tid < 16){
      int ws = wsum[tid];
      #pragma unroll
      for (int off = 1; off < 16; off <<= 1){
        int t = __shfl_up(ws, off);
        if (tid >= off) ws += t;
      }
      wsum[tid] = ws;
    }
    __syncthreads();
    int waveoff = (wid > 0) ? wsum[wid - 1] : 0;
    if (i < n) rowp[i] = running + waveoff + s - v;
    running += wsum[15];
    __syncthreads();
  }
  if (tid == 0) rowp[n] = running;
}

// K4: scatter (src, eattr) into CSR order keyed by dst
__global__ __launch_bounds__(256) void k_scatter(
    const int* __restrict__ srcI, const int* __restrict__ dstI,
    const float* __restrict__ eattr, const int* __restrict__ rowp,
    int* __restrict__ fill, int2* __restrict__ sortedSE, int E){
  int e = blockIdx.x * blockDim.x + threadIdx.x;
  if (e >= E) return;
  int t = dstI[e];
  int pos = rowp[t] + atomicAdd(&fill[t], 1);
  sortedSE[pos] = make_int2(srcI[e], __float_as_int(eattr[e]));
}

// K5: fused attention per dst row — one wave per node.
// scores (coalesced x4 gathers + butterfly reduce) -> online softmax ->
// weighted aggregation of x2 (coalesced gathers), added into node_acc.
__global__ __launch_bounds__(256) void k_attn(
    const float* __restrict__ x2, const float* __restrict__ x3,
    const float* __restrict__ x4, const float* __restrict__ p5,
    const float* __restrict__ pb, const int2* __restrict__ sortedSE,
    const int* __restrict__ rowp, float* __restrict__ node_acc, int n){
  int t = blockIdx.x * 4 + (threadIdx.x >> 6);
  int lane = threadIdx.x & 63;
  if (t >= n) return;
  int beg = rowp[t], end = rowp[t + 1];
  if (beg == end) return;

  const float* r3 = x3 + (size_t)t * D;
  float v0 = r3[lane];
  float v1 = (lane < 32) ? r3[64 + lane] : 0.0f;
  float p5t = p5[t], pbt = pb[t];

  float m = -INFINITY;   // uniform across lanes
  float dsum = 0.0f;     // uniform
  float a0 = 0.0f, a1 = 0.0f;

  for (int c0 = beg; c0 < end; c0 += 64){
    int c1 = min(c0 + 64, end);
    int cn = c1 - c0;
    // pass A: scores for this chunk, one kept per lane
    float my_sc = -INFINITY;
    float m_c = -INFINITY;
    for (int i = 0; i < cn; ++i){
      int2 se = sortedSE[c0 + i];
      const float* r4 = x4 + (size_t)se.x * D;
      float u0 = r4[lane];
      float u1 = (lane < 32) ? r4[64 + lane] : 0.0f;
      float sum = v0 * u0 + v1 * u1;
      #pragma unroll
      for (int off = 32; off; off >>= 1) sum += __shfl_xor(sum, off);
      float sc = (sum + __int_as_float(se.y) * p5t + pbt) * RSQ;
      m_c = fmaxf(m_c, sc);
      if (lane == i) my_sc = sc;
    }
    // merge running softmax state
    float m_new = fmaxf(m, m_c);
    float r = expf(m - m_new);   // 0 when m = -inf
    dsum *= r; a0 *= r; a1 *= r;
    m = m_new;
    // pass B: exp-weighted aggregation of x2
    for (int i = 0; i < cn; ++i){
      float w = expf(__shfl(my_sc, i) - m);
      int2 se = sortedSE[c0 + i];
      const float* r2 = x2 + (size_t)se.x * D;
      float u0 = r2[lane];
      float u1 = (lane < 32) ? r2[64 + lane] : 0.0f;
      dsum += w;
      a0 += w * u0;
      a1 += w * u1;
    }
  }
  float inv = 1.0f / (dsum + 1e-16f);
  size_t o = (size_t)t * D + lane;
  node_acc[o] += a0 * inv;
  if (lane < 32) node_acc[o + 64] += a1 * inv;
}

// K6: per-graph partial sums (batch is sorted; binary-search boundaries)
__global__ __launch_bounds__(96) void k_pool(
    const float* __restrict__ node_out, const int* __restrict__ batch,
    float* __restrict__ sums, int n){
  int g = blockIdx.x;
  int chunk = blockIdx.y, nch = gridDim.y;
  int lo = lbound(batch, n, g);
  int hi = lbound(batch, n, g + 1);
  int cnt = hi - lo;
  if (cnt <= 0) return;
  int per = (cnt + nch - 1) / nch;
  int b = lo + chunk * per;
  int e = min(b + per, hi);
  if (b >= e) return;
  int d = threadIdx.x;
  float s = 0.0f;
  for (int r = b; r < e; ++r) s += node_out[(size_t)r * D + d];
  atomicAdd(&sums[g * D + d], s);
}

// K7: divide by counts
__global__ __launch_bounds__(256) void k_final(
    const float* __restrict__ sums, const int* __restrict__ batch,
    float* __restrict__ out, int n, int total){
  int i = blockIdx.x * blockDim.x + threadIdx.x;
  if (i >= total) return;
  int g = i / D;
  int lo = lbound(batch, n, g);
  int hi = lbound(batch, n, g + 1);
  float c = (float)((hi - lo) > 1 ? (hi - lo) : 1);
  out[i] = sums[i] / c;
}

extern "C" void kernel_launch(void* const* d_in, const int* in_sizes, int n_in,
                              void* d_out, int out_size, void* d_ws, size_t ws_size,
                              hipStream_t stream){
  const float* x     = (const float*)d_in[0];
  const int*   eidx  = (const int*)d_in[1];
  const float* eattr = (const float*)d_in[2];
  const int*   batch = (const int*)d_in[3];
  const float* w1 = (const float*)d_in[4];
  const float* b1 = (const float*)d_in[5];
  const float* w2 = (const float*)d_in[6];
  const float* b2 = (const float*)d_in[7];
  const float* w3 = (const float*)d_in[8];
  const float* b3 = (const float*)d_in[9];
  const float* w4 = (const float*)d_in[10];
  const float* b4 = (const float*)d_in[11];
  const float* w5 = (const float*)d_in[12];
  const float* b5 = (const float*)d_in[13];
  float* out = (float*)d_out;

  const int N = in_sizes[0] / D;
  const int E = in_sizes[2];          // edge_attr is [E,1]
  const int* srcI = eidx;
  const int* dstI = eidx + E;

  // workspace layout
  char* base = (char*)d_ws;
  size_t off = 0;
  auto alloc = [&](size_t bytes) -> char* {
    char* p = base + off;
    off = (off + bytes + 255) & ~(size_t)255;
    return p;
  };
  // zeroed region first (one contiguous memset)
  char* zbase = base;
  int*   deg  = (int*)alloc((size_t)N * 4);
  int*   fill = (int*)alloc((size_t)N * 4);
  float* sums = (float*)alloc((size_t)out_size * 4);
  size_t zbytes = off;
  // rest
  float* node_acc = (float*)alloc((size_t)N * D * 4);
  float* x2v      = (float*)alloc((size_t)N * D * 4);
  float* x3v      = (float*)alloc((size_t)N * D * 4);
  float* x4v      = (float*)alloc((size_t)N * D * 4);
  float* p5       = (float*)alloc((size_t)N * 4);
  float* pb       = (float*)alloc((size_t)N * 4);
  int*   rowp     = (int*)alloc((size_t)(N + 1) * 4);
  int2*  sortedSE = (int2*)alloc((size_t)E * 8);
  (void)ws_size; (void)n_in;

  hipMemsetAsync(zbase, 0, zbytes, stream);

  k_transform<<<dim3((N + NPB - 1) / NPB), dim3(D), 0, stream>>>(
      x, w1, b1, w2, b2, w3, b3, w4, b4, node_acc, x2v, x3v, x4v, N);
  k_p5<<<dim3((N + 3) / 4), dim3(256), 0, stream>>>(x3v, w5, b5, p5, pb, N);
  k_deg<<<dim3((E + 255) / 256), dim3(256), 0, stream>>>(dstI, deg, E);
  k_scan<<<dim3(1), dim3(1024), 0, stream>>>(deg, rowp, N);
  k_scatter<<<dim3((E + 255) / 256), dim3(256), 0, stream>>>(
      srcI, dstI, eattr, rowp, fill, sortedSE, E);
  k_attn<<<dim3((N + 3) / 4), dim3(256), 0, stream>>>(
      x2v, x3v, x4v, p5, pb, sortedSE, rowp, node_acc, N);
  k_pool<<<dim3(out_size / D, 32), dim3(D), 0, stream>>>(node_acc, batch, sums, N);
  k_final<<<dim3((out_size + 255) / 256), dim3(256), 0, stream>>>(
      sums, batch, out, N, out_size);
}

// Round 3
// 376.652 us; speedup vs baseline: 1.4928x; 1.3533x over previous
//
#include <hip/hip_runtime.h>
#include <math.h>

#define D 96
#define TN 16   // nodes per transform block
#define RSQ 0.10206207261596577f  // 1/sqrt(96)

__device__ __forceinline__ int lbound(const int* __restrict__ a, int n, int v){
  int lo = 0, hi = n;
  while (lo < hi){ int mid = (lo + hi) >> 1; if (a[mid] < v) lo = mid + 1; else hi = mid; }
  return lo;
}

// K1: node transforms. acc = x@w1+b1 ; x2o/x3o/x4o = x@w{2,3,4}+b{2,3,4}
// 384 threads = 6 full waves; 16 nodes/block; thread = (slot 0..3, d 0..95), 4 nodes per thread.
__global__ __launch_bounds__(384) void k_transform(
    const float* __restrict__ x,
    const float* __restrict__ w1, const float* __restrict__ b1,
    const float* __restrict__ w2, const float* __restrict__ b2,
    const float* __restrict__ w3, const float* __restrict__ b3,
    const float* __restrict__ w4, const float* __restrict__ b4,
    float* __restrict__ acc, float* __restrict__ x2o,
    float* __restrict__ x3o, float* __restrict__ x4o, int n){
  __shared__ float xs[TN][D + 1];
  int tid = threadIdx.x;
  int d = tid % D;
  int slot = tid / D;
  int n0 = blockIdx.x * TN;
  for (int e = tid; e < TN * D; e += 384){
    int r = e / D, c = e % D;
    int node = n0 + r;
    xs[r][c] = (node < n) ? x[(size_t)node * D + c] : 0.0f;
  }
  __syncthreads();
  float a1[4] = {0,0,0,0}, a2[4] = {0,0,0,0}, a3[4] = {0,0,0,0}, a4[4] = {0,0,0,0};
  for (int k = 0; k < D; ++k){
    float v1 = w1[k * D + d], v2 = w2[k * D + d], v3 = w3[k * D + d], v4 = w4[k * D + d];
    #pragma unroll
    for (int i = 0; i < 4; ++i){
      float xv = xs[slot * 4 + i][k];
      a1[i] += xv * v1; a2[i] += xv * v2; a3[i] += xv * v3; a4[i] += xv * v4;
    }
  }
  float bb1 = b1[d], bb2 = b2[d], bb3 = b3[d], bb4 = b4[d];
  #pragma unroll
  for (int i = 0; i < 4; ++i){
    int r = n0 + slot * 4 + i;
    if (r < n){
      size_t o = (size_t)r * D + d;
      acc[o] = a1[i] + bb1;
      x2o[o] = a2[i] + bb2;
      x3o[o] = a3[i] + bb3;
      x4o[o] = a4[i] + bb4;
    }
  }
}

// K1b: per-node scalars p5 = dot(x3, w5row), pb = dot(x3, w5b). One wave per node.
__global__ __launch_bounds__(256) void k_p5(
    const float* __restrict__ x3, const float* __restrict__ w5,
    const float* __restrict__ w5b, float* __restrict__ p5,
    float* __restrict__ pb, int n){
  int node = blockIdx.x * 4 + (threadIdx.x >> 6);
  int lane = threadIdx.x & 63;
  if (node >= n) return;
  const float* row = x3 + (size_t)node * D;
  float v0 = row[lane];
  float s5 = v0 * w5[lane];
  float sb = v0 * w5b[lane];
  if (lane < 32){
    float v1 = row[64 + lane];
    s5 += v1 * w5[64 + lane];
    sb += v1 * w5b[64 + lane];
  }
  #pragma unroll
  for (int off = 32; off > 0; off >>= 1){
    s5 += __shfl_down(s5, off);
    sb += __shfl_down(sb, off);
  }
  if (lane == 0){ p5[node] = s5; pb[node] = sb; }
}

// K2: degree histogram over dst
__global__ __launch_bounds__(256) void k_deg(
    const int* __restrict__ dstI, int* __restrict__ deg, int E){
  int e = blockIdx.x * blockDim.x + threadIdx.x;
  if (e >= E) return;
  atomicAdd(&deg[dstI[e]], 1);
}

// K3a: per-block exclusive scan (256 elements/block) + block totals
__global__ __launch_bounds__(256) void k_scanA(
    const int* __restrict__ deg, int* __restrict__ rowp,
    int* __restrict__ partials, int n){
  __shared__ int ws[4];
  int tid = threadIdx.x, lane = tid & 63, wid = tid >> 6;
  int i = blockIdx.x * 256 + tid;
  int v = (i < n) ? deg[i] : 0;
  int s = v;
  #pragma unroll
  for (int off = 1; off < 64; off <<= 1){ int u = __shfl_up(s, off); if (lane >= off) s += u; }
  if (lane == 63) ws[wid] = s;
  __syncthreads();
  if (tid < 4){
    int u = ws[tid];
    #pragma unroll
    for (int off = 1; off < 4; off <<= 1){ int q = __shfl_up(u, off); if (tid >= off) u += q; }
    ws[tid] = u;
  }
  __syncthreads();
  int woff = wid ? ws[wid - 1] : 0;
  if (i < n) rowp[i] = woff + s - v;
  if (tid == 255) partials[blockIdx.x] = ws[3];
}

// K3b: exclusive scan of block totals (in place) + grand total -> rowp[n]
__global__ __launch_bounds__(256) void k_scanB(
    int* __restrict__ partials, int* __restrict__ rowp, int nb, int n){
  __shared__ int ws[4];
  int tid = threadIdx.x, lane = tid & 63, wid = tid >> 6;
  int running = 0;
  for (int base = 0; base < nb; base += 256){
    int i = base + tid;
    int v = (i < nb) ? partials[i] : 0;
    int s = v;
    #pragma unroll
    for (int off = 1; off < 64; off <<= 1){ int u = __shfl_up(s, off); if (lane >= off) s += u; }
    if (lane == 63) ws[wid] = s;
    __syncthreads();
    if (tid < 4){
      int u = ws[tid];
      #pragma unroll
      for (int off = 1; off < 4; off <<= 1){ int q = __shfl_up(u, off); if (tid >= off) u += q; }
      ws[tid] = u;
    }
    __syncthreads();
    int woff = wid ? ws[wid - 1] : 0;
    if (i < nb) partials[i] = running + woff + s - v;
    running += ws[3];
    __syncthreads();
  }
  if (tid == 0) rowp[n] = running;
}

// K3c: add block offsets
__global__ __launch_bounds__(256) void k_scanC(
    const int* __restrict__ partials, int* __restrict__ rowp, int n){
  int i = blockIdx.x * 256 + threadIdx.x;
  if (i < n) rowp[i] += partials[blockIdx.x];
}

// K4: scatter (src, eattr) into CSR order keyed by dst
__global__ __launch_bounds__(256) void k_scatter(
    const int* __restrict__ srcI, const int* __restrict__ dstI,
    const float* __restrict__ eattr, const int* __restrict__ rowp,
    int* __restrict__ fill, int2* __restrict__ sortedSE, int E){
  int e = blockIdx.x * blockDim.x + threadIdx.x;
  if (e >= E) return;
  int t = dstI[e];
  int pos = rowp[t] + atomicAdd(&fill[t], 1);
  sortedSE[pos] = make_int2(srcI[e], __float_as_int(eattr[e]));
}

// K5: fused attention per dst row — one wave per node, 16 lanes per edge,
// 4 edges in flight; single fused pass with online softmax (skip-rescale).
__global__ __launch_bounds__(256) void k_attn(
    const float* __restrict__ x2, const float* __restrict__ x3,
    const float* __restrict__ x4, const float* __restrict__ p5,
    const float* __restrict__ pb, const int2* __restrict__ sortedSE,
    const int* __restrict__ rowp, float* __restrict__ node_acc, int n){
  int t = blockIdx.x * 4 + (threadIdx.x >> 6);
  int lane = threadIdx.x & 63;
  if (t >= n) return;
  int beg = rowp[t], end = rowp[t + 1];
  if (beg == end) return;
  int j = lane & 15;

  const float* r3 = x3 + (size_t)t * D;
  float v0 = r3[j],      v1 = r3[j + 16], v2 = r3[j + 32];
  float v3 = r3[j + 48], v4 = r3[j + 64], v5 = r3[j + 80];
  float p5t = p5[t], pbt = pb[t];

  float m = -INFINITY, dsum = 0.0f;
  float a0 = 0, a1 = 0, a2 = 0, a3 = 0, a4 = 0, a5 = 0;

  for (int c = beg; c < end; c += 4){
    int g = lane >> 4;
    int ei = c + g;
    bool act = ei < end;
    int2 se = sortedSE[act ? ei : end - 1];
    const float* r4 = x4 + (size_t)se.x * D;
    float s = v0 * r4[j]      + v1 * r4[j + 16] + v2 * r4[j + 32]
            + v3 * r4[j + 48] + v4 * r4[j + 64] + v5 * r4[j + 80];
    s += __shfl_xor(s, 1); s += __shfl_xor(s, 2);
    s += __shfl_xor(s, 4); s += __shfl_xor(s, 8);
    float sc = act ? (s + __int_as_float(se.y) * p5t + pbt) * RSQ : -INFINITY;
    float mc = fmaxf(sc, __shfl_xor(sc, 16));
    mc = fmaxf(mc, __shfl_xor(mc, 32));
    if (mc > m){
      float r = __expf(m - mc);     // 0 on first iteration (m = -inf)
      dsum *= r; a0 *= r; a1 *= r; a2 *= r; a3 *= r; a4 *= r; a5 *= r;
      m = mc;
    }
    float w = __expf(sc - m);       // 0 for inactive groups
    dsum += w;
    const float* r2 = x2 + (size_t)se.x * D;
    a0 += w * r2[j];      a1 += w * r2[j + 16]; a2 += w * r2[j + 32];
    a3 += w * r2[j + 48]; a4 += w * r2[j + 64]; a5 += w * r2[j + 80];
  }
  // reduce across the 4 groups
  a0 += __shfl_xor(a0, 16); a0 += __shfl_xor(a0, 32);
  a1 += __shfl_xor(a1, 16); a1 += __shfl_xor(a1, 32);
  a2 += __shfl_xor(a2, 16); a2 += __shfl_xor(a2, 32);
  a3 += __shfl_xor(a3, 16); a3 += __shfl_xor(a3, 32);
  a4 += __shfl_xor(a4, 16); a4 += __shfl_xor(a4, 32);
  a5 += __shfl_xor(a5, 16); a5 += __shfl_xor(a5, 32);
  dsum += __shfl_xor(dsum, 16); dsum += __shfl_xor(dsum, 32);
  float inv = 1.0f / (dsum + 1e-16f);
  if (lane < 16){
    size_t o = (size_t)t * D + j;
    node_acc[o]      += a0 * inv;
    node_acc[o + 16] += a1 * inv;
    node_acc[o + 32] += a2 * inv;
    node_acc[o + 48] += a3 * inv;
    node_acc[o + 64] += a4 * inv;
    node_acc[o + 80] += a5 * inv;
  }
}

// K6: per-graph partial sums (batch is sorted; binary-search boundaries)
__global__ __launch_bounds__(96) void k_pool(
    const float* __restrict__ node_out, const int* __restrict__ batch,
    float* __restrict__ sums, int n){
  int g = blockIdx.x;
  int chunk = blockIdx.y, nch = gridDim.y;
  int lo = lbound(batch, n, g);
  int hi = lbound(batch, n, g + 1);
  int cnt = hi - lo;
  if (cnt <= 0) return;
  int per = (cnt + nch - 1) / nch;
  int b = lo + chunk * per;
  int e = min(b + per, hi);
  if (b >= e) return;
  int d = threadIdx.x;
  float s = 0.0f;
  for (int r = b; r < e; ++r) s += node_out[(size_t)r * D + d];
  atomicAdd(&sums[g * D + d], s);
}

// K7: divide by counts
__global__ __launch_bounds__(256) void k_final(
    const float* __restrict__ sums, const int* __restrict__ batch,
    float* __restrict__ out, int n, int total){
  int i = blockIdx.x * blockDim.x + threadIdx.x;
  if (i >= total) return;
  int g = i / D;
  int lo = lbound(batch, n, g);
  int hi = lbound(batch, n, g + 1);
  float c = (float)((hi - lo) > 1 ? (hi - lo) : 1);
  out[i] = sums[i] / c;
}

extern "C" void kernel_launch(void* const* d_in, const int* in_sizes, int n_in,
                              void* d_out, int out_size, void* d_ws, size_t ws_size,
                              hipStream_t stream){
  const float* x     = (const float*)d_in[0];
  const int*   eidx  = (const int*)d_in[1];
  const float* eattr = (const float*)d_in[2];
  const int*   batch = (const int*)d_in[3];
  const float* w1 = (const float*)d_in[4];
  const float* b1 = (const float*)d_in[5];
  const float* w2 = (const float*)d_in[6];
  const float* b2 = (const float*)d_in[7];
  const float* w3 = (const float*)d_in[8];
  const float* b3 = (const float*)d_in[9];
  const float* w4 = (const float*)d_in[10];
  const float* b4 = (const float*)d_in[11];
  const float* w5 = (const float*)d_in[12];
  const float* b5 = (const float*)d_in[13];
  float* out = (float*)d_out;

  const int N = in_sizes[0] / D;
  const int E = in_sizes[2];
  const int* srcI = eidx;
  const int* dstI = eidx + E;
  const int NB = (N + 255) / 256;

  char* base = (char*)d_ws;
  size_t off = 0;
  auto alloc = [&](size_t bytes) -> char* {
    char* p = base + off;
    off = (off + bytes + 255) & ~(size_t)255;
    return p;
  };
  char* zbase = base;
  int*   deg  = (int*)alloc((size_t)N * 4);
  int*   fill = (int*)alloc((size_t)N * 4);
  float* sums = (float*)alloc((size_t)out_size * 4);
  size_t zbytes = off;
  float* node_acc = (float*)alloc((size_t)N * D * 4);
  float* x2v      = (float*)alloc((size_t)N * D * 4);
  float* x3v      = (float*)alloc((size_t)N * D * 4);
  float* x4v      = (float*)alloc((size_t)N * D * 4);
  float* p5       = (float*)alloc((size_t)N * 4);
  float* pb       = (float*)alloc((size_t)N * 4);
  int*   rowp     = (int*)alloc((size_t)(N + 1) * 4);
  int*   partials = (int*)alloc((size_t)(NB + 1) * 4);
  int2*  sortedSE = (int2*)alloc((size_t)E * 8);
  (void)ws_size; (void)n_in;

  hipMemsetAsync(zbase, 0, zbytes, stream);

  k_transform<<<dim3((N + TN - 1) / TN), dim3(384), 0, stream>>>(
      x, w1, b1, w2, b2, w3, b3, w4, b4, node_acc, x2v, x3v, x4v, N);
  k_p5<<<dim3((N + 3) / 4), dim3(256), 0, stream>>>(x3v, w5, b5, p5, pb, N);
  k_deg<<<dim3((E + 255) / 256), dim3(256), 0, stream>>>(dstI, deg, E);
  k_scanA<<<dim3(NB), dim3(256), 0, stream>>>(deg, rowp, partials, N);
  k_scanB<<<dim3(1), dim3(256), 0, stream>>>(partials, rowp, NB, N);
  k_scanC<<<dim3(NB), dim3(256), 0, stream>>>(partials, rowp, N);
  k_scatter<<<dim3((E + 255) / 256), dim3(256), 0, stream>>>(
      srcI, dstI, eattr, rowp, fill, sortedSE, E);
  k_attn<<<dim3((N + 3) / 4), dim3(256), 0, stream>>>(
      x2v, x3v, x4v, p5, pb, sortedSE, rowp, node_acc, N);
  k_pool<<<dim3(out_size / D, 32), dim3(D), 0, stream>>>(node_acc, batch, sums, N);
  k_final<<<dim3((out_size + 255) / 256), dim3(256), 0, stream>>>(
      sums, batch, out, N, out_size);
}

// Round 4
// 337.101 us; speedup vs baseline: 1.6679x; 1.1173x over previous
//
#include <hip/hip_runtime.h>
#include <math.h>

#define D 96
#define RSQ 0.10206207261596577f  // 1/sqrt(96)
#define TSTRIDE 104               // padded LDS row stride (bf16 elems), 16B-aligned, breaks bank conflicts

typedef __attribute__((ext_vector_type(8))) short short8;
typedef __attribute__((ext_vector_type(4))) float f32x4;

__device__ __forceinline__ unsigned short f2bf(float f){
  unsigned u = __float_as_uint(f);
  unsigned r = (u + 0x7fff + ((u >> 16) & 1)) >> 16;  // RNE
  return (unsigned short)r;
}
__device__ __forceinline__ float bf2f(unsigned short h){
  return __uint_as_float(((unsigned)h) << 16);
}
__device__ __forceinline__ int lbound(const int* __restrict__ a, int n, int v){
  int lo = 0, hi = n;
  while (lo < hi){ int mid = (lo + hi) >> 1; if (a[mid] < v) lo = mid + 1; else hi = mid; }
  return lo;
}

// K0: weight prep — transpose w_m[96][96] (k-major) to wt[m][n][k] (k-contiguous), split hi/lo bf16
__global__ __launch_bounds__(256) void k_wprep(
    const float* __restrict__ w1, const float* __restrict__ w2,
    const float* __restrict__ w3, const float* __restrict__ w4,
    unsigned short* __restrict__ wt_h, unsigned short* __restrict__ wt_l){
  int idx = blockIdx.x * 256 + threadIdx.x;
  if (idx >= 4 * D * D) return;
  int m = idx / (D * D);
  int r = idx % (D * D);
  int nn = r / D, k = r % D;
  const float* w = (m == 0) ? w1 : (m == 1) ? w2 : (m == 2) ? w3 : w4;
  float v = w[k * D + nn];
  unsigned short h = f2bf(v);
  wt_h[idx] = h;
  wt_l[idx] = f2bf(v - bf2f(h));
}

// K1: node transforms via split-bf16 MFMA. Block = 16 nodes, 4 waves; wave w computes x@w_w (16x96).
// Wave 2 (x3) also computes fused p5 = dot(x3,w5), pb = dot(x3,b5).
__global__ __launch_bounds__(256) void k_transform_mfma(
    const float* __restrict__ x,
    const unsigned short* __restrict__ wt_h, const unsigned short* __restrict__ wt_l,
    const float* __restrict__ b1, const float* __restrict__ b2,
    const float* __restrict__ b3, const float* __restrict__ b4,
    const float* __restrict__ w5, const float* __restrict__ b5,
    float* __restrict__ acc_o, float* __restrict__ x2o,
    float* __restrict__ x3o, float* __restrict__ x4o,
    float* __restrict__ p5, float* __restrict__ pb, int n){
  __shared__ __align__(16) unsigned short xs_h[16][TSTRIDE];
  __shared__ __align__(16) unsigned short xs_l[16][TSTRIDE];
  int tid = threadIdx.x;
  int n0 = blockIdx.x * 16;
  for (int e = tid; e < 16 * D; e += 256){
    int r = e / D, c = e % D;
    int node = n0 + r;
    float v = (node < n) ? x[(size_t)node * D + c] : 0.0f;
    unsigned short h = f2bf(v);
    xs_h[r][c] = h;
    xs_l[r][c] = f2bf(v - bf2f(h));
  }
  __syncthreads();

  int wv = tid >> 6;        // which weight matrix (0..3)
  int lane = tid & 63;
  int lr = lane & 15;       // A row / B col / D col
  int kg = lane >> 4;       // k-group (0..3)

  f32x4 acc0 = {0,0,0,0}, acc1 = {0,0,0,0}, acc2 = {0,0,0,0};
  f32x4 acc3 = {0,0,0,0}, acc4 = {0,0,0,0}, acc5 = {0,0,0,0};
  const unsigned short* wtm_h = wt_h + (size_t)wv * D * D;
  const unsigned short* wtm_l = wt_l + (size_t)wv * D * D;

  #pragma unroll
  for (int k0 = 0; k0 < D; k0 += 32){
    int kb = k0 + kg * 8;
    short8 ah = *(const short8*)&xs_h[lr][kb];
    short8 al = *(const short8*)&xs_l[lr][kb];
    #pragma unroll
    for (int nc = 0; nc < 6; ++nc){
      int col = nc * 16 + lr;
      short8 bh = *(const short8*)(wtm_h + col * D + kb);
      short8 bl = *(const short8*)(wtm_l + col * D + kb);
      f32x4 a = (nc == 0) ? acc0 : (nc == 1) ? acc1 : (nc == 2) ? acc2
              : (nc == 3) ? acc3 : (nc == 4) ? acc4 : acc5;
      a = __builtin_amdgcn_mfma_f32_16x16x32_bf16(ah, bh, a, 0, 0, 0);
      a = __builtin_amdgcn_mfma_f32_16x16x32_bf16(ah, bl, a, 0, 0, 0);
      a = __builtin_amdgcn_mfma_f32_16x16x32_bf16(al, bh, a, 0, 0, 0);
      if (nc == 0) acc0 = a; else if (nc == 1) acc1 = a; else if (nc == 2) acc2 = a;
      else if (nc == 3) acc3 = a; else if (nc == 4) acc4 = a; else acc5 = a;
    }
  }

  const float* bias = (wv == 0) ? b1 : (wv == 1) ? b2 : (wv == 2) ? b3 : b4;
  float* outp = (wv == 0) ? acc_o : (wv == 1) ? x2o : (wv == 2) ? x3o : x4o;
  float p5p0 = 0, p5p1 = 0, p5p2 = 0, p5p3 = 0;
  float pbp0 = 0, pbp1 = 0, pbp2 = 0, pbp3 = 0;
  #pragma unroll
  for (int nc = 0; nc < 6; ++nc){
    int col = nc * 16 + lr;
    float bb = bias[col];
    float w5v = w5[col], b5v = b5[col];
    f32x4 a = (nc == 0) ? acc0 : (nc == 1) ? acc1 : (nc == 2) ? acc2
            : (nc == 3) ? acc3 : (nc == 4) ? acc4 : acc5;
    #pragma unroll
    for (int q = 0; q < 4; ++q){
      float v = a[q] + bb;
      int row = kg * 4 + q;
      if (n0 + row < n) outp[(size_t)(n0 + row) * D + col] = v;
      float t5 = v * w5v, tb = v * b5v;
      if (q == 0){ p5p0 += t5; pbp0 += tb; }
      else if (q == 1){ p5p1 += t5; pbp1 += tb; }
      else if (q == 2){ p5p2 += t5; pbp2 += tb; }
      else { p5p3 += t5; pbp3 += tb; }
    }
  }
  if (wv == 2){
    #pragma unroll
    for (int off = 1; off < 16; off <<= 1){
      p5p0 += __shfl_xor(p5p0, off); pbp0 += __shfl_xor(pbp0, off);
      p5p1 += __shfl_xor(p5p1, off); pbp1 += __shfl_xor(pbp1, off);
      p5p2 += __shfl_xor(p5p2, off); pbp2 += __shfl_xor(pbp2, off);
      p5p3 += __shfl_xor(p5p3, off); pbp3 += __shfl_xor(pbp3, off);
    }
    if (lr == 0){
      int row = kg * 4;
      if (n0 + row < n)     { p5[n0 + row]     = p5p0; pb[n0 + row]     = pbp0; }
      if (n0 + row + 1 < n) { p5[n0 + row + 1] = p5p1; pb[n0 + row + 1] = pbp1; }
      if (n0 + row + 2 < n) { p5[n0 + row + 2] = p5p2; pb[n0 + row + 2] = pbp2; }
      if (n0 + row + 3 < n) { p5[n0 + row + 3] = p5p3; pb[n0 + row + 3] = pbp3; }
    }
  }
}

// K2: degree histogram over dst
__global__ __launch_bounds__(256) void k_deg(
    const int* __restrict__ dstI, int* __restrict__ deg, int E){
  int e = blockIdx.x * blockDim.x + threadIdx.x;
  if (e >= E) return;
  atomicAdd(&deg[dstI[e]], 1);
}

// K3a: per-block exclusive scan (256 elements/block) + block totals
__global__ __launch_bounds__(256) void k_scanA(
    const int* __restrict__ deg, int* __restrict__ rowp,
    int* __restrict__ partials, int n){
  __shared__ int ws[4];
  int tid = threadIdx.x, lane = tid & 63, wid = tid >> 6;
  int i = blockIdx.x * 256 + tid;
  int v = (i < n) ? deg[i] : 0;
  int s = v;
  #pragma unroll
  for (int off = 1; off < 64; off <<= 1){ int u = __shfl_up(s, off); if (lane >= off) s += u; }
  if (lane == 63) ws[wid] = s;
  __syncthreads();
  if (tid < 4){
    int u = ws[tid];
    #pragma unroll
    for (int off = 1; off < 4; off <<= 1){ int q = __shfl_up(u, off); if (tid >= off) u += q; }
    ws[tid] = u;
  }
  __syncthreads();
  int woff = wid ? ws[wid - 1] : 0;
  if (i < n) rowp[i] = woff + s - v;
  if (tid == 255) partials[blockIdx.x] = ws[3];
}

// K3b: exclusive scan of block totals (in place) + grand total -> rowp[n]
__global__ __launch_bounds__(256) void k_scanB(
    int* __restrict__ partials, int* __restrict__ rowp, int nb, int n){
  __shared__ int ws[4];
  int tid = threadIdx.x, lane = tid & 63, wid = tid >> 6;
  int running = 0;
  for (int base = 0; base < nb; base += 256){
    int i = base + tid;
    int v = (i < nb) ? partials[i] : 0;
    int s = v;
    #pragma unroll
    for (int off = 1; off < 64; off <<= 1){ int u = __shfl_up(s, off); if (lane >= off) s += u; }
    if (lane == 63) ws[wid] = s;
    __syncthreads();
    if (tid < 4){
      int u = ws[tid];
      #pragma unroll
      for (int off = 1; off < 4; off <<= 1){ int q = __shfl_up(u, off); if (tid >= off) u += q; }
      ws[tid] = u;
    }
    __syncthreads();
    int woff = wid ? ws[wid - 1] : 0;
    if (i < nb) partials[i] = running + woff + s - v;
    running += ws[3];
    __syncthreads();
  }
  if (tid == 0) rowp[n] = running;
}

// K3c: add block offsets
__global__ __launch_bounds__(256) void k_scanC(
    const int* __restrict__ partials, int* __restrict__ rowp, int n){
  int i = blockIdx.x * 256 + threadIdx.x;
  if (i < n) rowp[i] += partials[blockIdx.x];
}

// K4: scatter (src, eattr) into CSR order keyed by dst
__global__ __launch_bounds__(256) void k_scatter(
    const int* __restrict__ srcI, const int* __restrict__ dstI,
    const float* __restrict__ eattr, const int* __restrict__ rowp,
    int* __restrict__ fill, int2* __restrict__ sortedSE, int E){
  int e = blockIdx.x * blockDim.x + threadIdx.x;
  if (e >= E) return;
  int t = dstI[e];
  int pos = rowp[t] + atomicAdd(&fill[t], 1);
  sortedSE[pos] = make_int2(srcI[e], __float_as_int(eattr[e]));
}

// K5: fused attention per dst row — one wave per node, 16 lanes per edge,
// 4 edges in flight; single fused pass with online softmax (skip-rescale).
__global__ __launch_bounds__(256) void k_attn(
    const float* __restrict__ x2, const float* __restrict__ x3,
    const float* __restrict__ x4, const float* __restrict__ p5,
    const float* __restrict__ pb, const int2* __restrict__ sortedSE,
    const int* __restrict__ rowp, float* __restrict__ node_acc, int n){
  int t = blockIdx.x * 4 + (threadIdx.x >> 6);
  int lane = threadIdx.x & 63;
  if (t >= n) return;
  int beg = rowp[t], end = rowp[t + 1];
  if (beg == end) return;
  int j = lane & 15;

  const float* r3 = x3 + (size_t)t * D;
  float v0 = r3[j],      v1 = r3[j + 16], v2 = r3[j + 32];
  float v3 = r3[j + 48], v4 = r3[j + 64], v5 = r3[j + 80];
  float p5t = p5[t], pbt = pb[t];

  float m = -INFINITY, dsum = 0.0f;
  float a0 = 0, a1 = 0, a2 = 0, a3 = 0, a4 = 0, a5 = 0;

  for (int c = beg; c < end; c += 4){
    int g = lane >> 4;
    int ei = c + g;
    bool act = ei < end;
    int2 se = sortedSE[act ? ei : end - 1];
    const float* r4 = x4 + (size_t)se.x * D;
    float s = v0 * r4[j]      + v1 * r4[j + 16] + v2 * r4[j + 32]
            + v3 * r4[j + 48] + v4 * r4[j + 64] + v5 * r4[j + 80];
    s += __shfl_xor(s, 1); s += __shfl_xor(s, 2);
    s += __shfl_xor(s, 4); s += __shfl_xor(s, 8);
    float sc = act ? (s + __int_as_float(se.y) * p5t + pbt) * RSQ : -INFINITY;
    float mc = fmaxf(sc, __shfl_xor(sc, 16));
    mc = fmaxf(mc, __shfl_xor(mc, 32));
    if (mc > m){
      float r = __expf(m - mc);     // 0 on first iteration (m = -inf)
      dsum *= r; a0 *= r; a1 *= r; a2 *= r; a3 *= r; a4 *= r; a5 *= r;
      m = mc;
    }
    float w = __expf(sc - m);       // 0 for inactive groups
    dsum += w;
    const float* r2 = x2 + (size_t)se.x * D;
    a0 += w * r2[j];      a1 += w * r2[j + 16]; a2 += w * r2[j + 32];
    a3 += w * r2[j + 48]; a4 += w * r2[j + 64]; a5 += w * r2[j + 80];
  }
  a0 += __shfl_xor(a0, 16); a0 += __shfl_xor(a0, 32);
  a1 += __shfl_xor(a1, 16); a1 += __shfl_xor(a1, 32);
  a2 += __shfl_xor(a2, 16); a2 += __shfl_xor(a2, 32);
  a3 += __shfl_xor(a3, 16); a3 += __shfl_xor(a3, 32);
  a4 += __shfl_xor(a4, 16); a4 += __shfl_xor(a4, 32);
  a5 += __shfl_xor(a5, 16); a5 += __shfl_xor(a5, 32);
  dsum += __shfl_xor(dsum, 16); dsum += __shfl_xor(dsum, 32);
  float inv = 1.0f / (dsum + 1e-16f);
  if (lane < 16){
    size_t o = (size_t)t * D + j;
    node_acc[o]      += a0 * inv;
    node_acc[o + 16] += a1 * inv;
    node_acc[o + 32] += a2 * inv;
    node_acc[o + 48] += a3 * inv;
    node_acc[o + 64] += a4 * inv;
    node_acc[o + 80] += a5 * inv;
  }
}

// K6: per-graph partial sums (batch is sorted; binary-search boundaries)
__global__ __launch_bounds__(96) void k_pool(
    const float* __restrict__ node_out, const int* __restrict__ batch,
    float* __restrict__ sums, int n){
  int g = blockIdx.x;
  int chunk = blockIdx.y, nch = gridDim.y;
  int lo = lbound(batch, n, g);
  int hi = lbound(batch, n, g + 1);
  int cnt = hi - lo;
  if (cnt <= 0) return;
  int per = (cnt + nch - 1) / nch;
  int b = lo + chunk * per;
  int e = min(b + per, hi);
  if (b >= e) return;
  int d = threadIdx.x;
  float s = 0.0f;
  for (int r = b; r < e; ++r) s += node_out[(size_t)r * D + d];
  atomicAdd(&sums[g * D + d], s);
}

// K7: divide by counts
__global__ __launch_bounds__(256) void k_final(
    const float* __restrict__ sums, const int* __restrict__ batch,
    float* __restrict__ out, int n, int total){
  int i = blockIdx.x * blockDim.x + threadIdx.x;
  if (i >= total) return;
  int g = i / D;
  int lo = lbound(batch, n, g);
  int hi = lbound(batch, n, g + 1);
  float c = (float)((hi - lo) > 1 ? (hi - lo) : 1);
  out[i] = sums[i] / c;
}

extern "C" void kernel_launch(void* const* d_in, const int* in_sizes, int n_in,
                              void* d_out, int out_size, void* d_ws, size_t ws_size,
                              hipStream_t stream){
  const float* x     = (const float*)d_in[0];
  const int*   eidx  = (const int*)d_in[1];
  const float* eattr = (const float*)d_in[2];
  const int*   batch = (const int*)d_in[3];
  const float* w1 = (const float*)d_in[4];
  const float* b1 = (const float*)d_in[5];
  const float* w2 = (const float*)d_in[6];
  const float* b2 = (const float*)d_in[7];
  const float* w3 = (const float*)d_in[8];
  const float* b3 = (const float*)d_in[9];
  const float* w4 = (const float*)d_in[10];
  const float* b4 = (const float*)d_in[11];
  const float* w5 = (const float*)d_in[12];
  const float* b5 = (const float*)d_in[13];
  float* out = (float*)d_out;

  const int N = in_sizes[0] / D;
  const int E = in_sizes[2];
  const int* srcI = eidx;
  const int* dstI = eidx + E;
  const int NB = (N + 255) / 256;

  char* base = (char*)d_ws;
  size_t off = 0;
  auto alloc = [&](size_t bytes) -> char* {
    char* p = base + off;
    off = (off + bytes + 255) & ~(size_t)255;
    return p;
  };
  char* zbase = base;
  int*   deg  = (int*)alloc((size_t)N * 4);
  int*   fill = (int*)alloc((size_t)N * 4);
  float* sums = (float*)alloc((size_t)out_size * 4);
  size_t zbytes = off;
  float* node_acc = (float*)alloc((size_t)N * D * 4);
  float* x2v      = (float*)alloc((size_t)N * D * 4);
  float* x3v      = (float*)alloc((size_t)N * D * 4);
  float* x4v      = (float*)alloc((size_t)N * D * 4);
  float* p5       = (float*)alloc((size_t)N * 4);
  float* pb       = (float*)alloc((size_t)N * 4);
  int*   rowp     = (int*)alloc((size_t)(N + 1) * 4);
  int*   partials = (int*)alloc((size_t)(NB + 1) * 4);
  int2*  sortedSE = (int2*)alloc((size_t)E * 8);
  unsigned short* wt_h = (unsigned short*)alloc((size_t)4 * D * D * 2);
  unsigned short* wt_l = (unsigned short*)alloc((size_t)4 * D * D * 2);
  (void)ws_size; (void)n_in;

  hipMemsetAsync(zbase, 0, zbytes, stream);

  k_wprep<<<dim3((4 * D * D + 255) / 256), dim3(256), 0, stream>>>(
      w1, w2, w3, w4, wt_h, wt_l);
  k_transform_mfma<<<dim3((N + 15) / 16), dim3(256), 0, stream>>>(
      x, wt_h, wt_l, b1, b2, b3, b4, w5, b5,
      node_acc, x2v, x3v, x4v, p5, pb, N);
  k_deg<<<dim3((E + 255) / 256), dim3(256), 0, stream>>>(dstI, deg, E);
  k_scanA<<<dim3(NB), dim3(256), 0, stream>>>(deg, rowp, partials, N);
  k_scanB<<<dim3(1), dim3(256), 0, stream>>>(partials, rowp, NB, N);
  k_scanC<<<dim3(NB), dim3(256), 0, stream>>>(partials, rowp, N);
  k_scatter<<<dim3((E + 255) / 256), dim3(256), 0, stream>>>(
      srcI, dstI, eattr, rowp, fill, sortedSE, E);
  k_attn<<<dim3((N + 3) / 4), dim3(256), 0, stream>>>(
      x2v, x3v, x4v, p5, pb, sortedSE, rowp, node_acc, N);
  k_pool<<<dim3(out_size / D, 32), dim3(D), 0, stream>>>(node_acc, batch, sums, N);
  k_final<<<dim3((out_size + 255) / 256), dim3(256), 0, stream>>>(
      sums, batch, out, N, out_size);
}

// Round 5
// 313.031 us; speedup vs baseline: 1.7962x; 1.0769x over previous
//
#include <hip/hip_runtime.h>
#include <math.h>

#define D 96
#define RSQ 0.10206207261596577f  // 1/sqrt(96)
#define TSTRIDE 104               // padded LDS row stride (bf16 elems)

typedef __attribute__((ext_vector_type(8))) short short8;
typedef __attribute__((ext_vector_type(4))) float f32x4;

__device__ __forceinline__ unsigned short f2bf(float f){
  unsigned u = __float_as_uint(f);
  unsigned r = (u + 0x7fff + ((u >> 16) & 1)) >> 16;  // RNE
  return (unsigned short)r;
}
__device__ __forceinline__ float bf2f(unsigned short h){
  return __uint_as_float(((unsigned)h) << 16);
}
__device__ __forceinline__ float bflo(unsigned u){ return __uint_as_float(u << 16); }
__device__ __forceinline__ float bfhi(unsigned u){ return __uint_as_float(u & 0xffff0000u); }
__device__ __forceinline__ int lbound(const int* __restrict__ a, int n, int v){
  int lo = 0, hi = n;
  while (lo < hi){ int mid = (lo + hi) >> 1; if (a[mid] < v) lo = mid + 1; else hi = mid; }
  return lo;
}

// K0: weight prep — transpose w_m[96][96] to [m][n][k] (k-contiguous), split hi/lo bf16
__global__ __launch_bounds__(256) void k_wprep(
    const float* __restrict__ w1, const float* __restrict__ w2,
    const float* __restrict__ w3, const float* __restrict__ w4,
    unsigned short* __restrict__ wt_h, unsigned short* __restrict__ wt_l){
  int idx = blockIdx.x * 256 + threadIdx.x;
  if (idx >= 4 * D * D) return;
  int m = idx / (D * D);
  int r = idx % (D * D);
  int nn = r / D, k = r % D;
  const float* w = (m == 0) ? w1 : (m == 1) ? w2 : (m == 2) ? w3 : w4;
  float v = w[k * D + nn];
  unsigned short h = f2bf(v);
  wt_h[idx] = h;
  wt_l[idx] = f2bf(v - bf2f(h));
}

// K1: node transforms via split-bf16 MFMA. Block = 16 nodes, 4 waves; wave w computes x@w_w (16x96).
// x2/x4 written as bf16 (halves k_attn gather traffic); acc/x3 stay f32.
// Wave 2 (x3) also computes fused p5 = dot(x3,w5), pb = dot(x3,b5).
__global__ __launch_bounds__(256) void k_transform_mfma(
    const float* __restrict__ x,
    const unsigned short* __restrict__ wt_h, const unsigned short* __restrict__ wt_l,
    const float* __restrict__ b1, const float* __restrict__ b2,
    const float* __restrict__ b3, const float* __restrict__ b4,
    const float* __restrict__ w5, const float* __restrict__ b5,
    float* __restrict__ acc_o, unsigned short* __restrict__ x2o,
    float* __restrict__ x3o, unsigned short* __restrict__ x4o,
    float* __restrict__ p5, float* __restrict__ pb, int n){
  __shared__ __align__(16) unsigned short xs_h[16][TSTRIDE];
  __shared__ __align__(16) unsigned short xs_l[16][TSTRIDE];
  int tid = threadIdx.x;
  int n0 = blockIdx.x * 16;
  for (int e = tid; e < 16 * D; e += 256){
    int r = e / D, c = e % D;
    int node = n0 + r;
    float v = (node < n) ? x[(size_t)node * D + c] : 0.0f;
    unsigned short h = f2bf(v);
    xs_h[r][c] = h;
    xs_l[r][c] = f2bf(v - bf2f(h));
  }
  __syncthreads();

  int wv = tid >> 6;
  int lane = tid & 63;
  int lr = lane & 15;
  int kg = lane >> 4;

  f32x4 acc0 = {0,0,0,0}, acc1 = {0,0,0,0}, acc2 = {0,0,0,0};
  f32x4 acc3 = {0,0,0,0}, acc4 = {0,0,0,0}, acc5 = {0,0,0,0};
  const unsigned short* wtm_h = wt_h + (size_t)wv * D * D;
  const unsigned short* wtm_l = wt_l + (size_t)wv * D * D;

  #pragma unroll
  for (int k0 = 0; k0 < D; k0 += 32){
    int kb = k0 + kg * 8;
    short8 ah = *(const short8*)&xs_h[lr][kb];
    short8 al = *(const short8*)&xs_l[lr][kb];
    #pragma unroll
    for (int nc = 0; nc < 6; ++nc){
      int col = nc * 16 + lr;
      short8 bh = *(const short8*)(wtm_h + col * D + kb);
      short8 bl = *(const short8*)(wtm_l + col * D + kb);
      f32x4 a = (nc == 0) ? acc0 : (nc == 1) ? acc1 : (nc == 2) ? acc2
              : (nc == 3) ? acc3 : (nc == 4) ? acc4 : acc5;
      a = __builtin_amdgcn_mfma_f32_16x16x32_bf16(ah, bh, a, 0, 0, 0);
      a = __builtin_amdgcn_mfma_f32_16x16x32_bf16(ah, bl, a, 0, 0, 0);
      a = __builtin_amdgcn_mfma_f32_16x16x32_bf16(al, bh, a, 0, 0, 0);
      if (nc == 0) acc0 = a; else if (nc == 1) acc1 = a; else if (nc == 2) acc2 = a;
      else if (nc == 3) acc3 = a; else if (nc == 4) acc4 = a; else acc5 = a;
    }
  }

  const float* bias = (wv == 0) ? b1 : (wv == 1) ? b2 : (wv == 2) ? b3 : b4;
  float p5p0 = 0, p5p1 = 0, p5p2 = 0, p5p3 = 0;
  float pbp0 = 0, pbp1 = 0, pbp2 = 0, pbp3 = 0;
  #pragma unroll
  for (int nc = 0; nc < 6; ++nc){
    int col = nc * 16 + lr;
    float bb = bias[col];
    float w5v = w5[col], b5v = b5[col];
    f32x4 a = (nc == 0) ? acc0 : (nc == 1) ? acc1 : (nc == 2) ? acc2
            : (nc == 3) ? acc3 : (nc == 4) ? acc4 : acc5;
    #pragma unroll
    for (int q = 0; q < 4; ++q){
      float v = a[q] + bb;
      int row = kg * 4 + q;
      if (n0 + row < n){
        size_t o = (size_t)(n0 + row) * D + col;
        if (wv == 0) acc_o[o] = v;
        else if (wv == 1) x2o[o] = f2bf(v);
        else if (wv == 2) x3o[o] = v;
        else x4o[o] = f2bf(v);
      }
      float t5 = v * w5v, tb = v * b5v;
      if (q == 0){ p5p0 += t5; pbp0 += tb; }
      else if (q == 1){ p5p1 += t5; pbp1 += tb; }
      else if (q == 2){ p5p2 += t5; pbp2 += tb; }
      else { p5p3 += t5; pbp3 += tb; }
    }
  }
  if (wv == 2){
    #pragma unroll
    for (int off = 1; off < 16; off <<= 1){
      p5p0 += __shfl_xor(p5p0, off); pbp0 += __shfl_xor(pbp0, off);
      p5p1 += __shfl_xor(p5p1, off); pbp1 += __shfl_xor(pbp1, off);
      p5p2 += __shfl_xor(p5p2, off); pbp2 += __shfl_xor(pbp2, off);
      p5p3 += __shfl_xor(p5p3, off); pbp3 += __shfl_xor(pbp3, off);
    }
    if (lr == 0){
      int row = kg * 4;
      if (n0 + row < n)     { p5[n0 + row]     = p5p0; pb[n0 + row]     = pbp0; }
      if (n0 + row + 1 < n) { p5[n0 + row + 1] = p5p1; pb[n0 + row + 1] = pbp1; }
      if (n0 + row + 2 < n) { p5[n0 + row + 2] = p5p2; pb[n0 + row + 2] = pbp2; }
      if (n0 + row + 3 < n) { p5[n0 + row + 3] = p5p3; pb[n0 + row + 3] = pbp3; }
    }
  }
}

// K2: degree histogram over dst
__global__ __launch_bounds__(256) void k_deg(
    const int* __restrict__ dstI, int* __restrict__ deg, int E){
  int e = blockIdx.x * blockDim.x + threadIdx.x;
  if (e >= E) return;
  atomicAdd(&deg[dstI[e]], 1);
}

// K3a: per-block exclusive scan (256 elements/block) + block totals
__global__ __launch_bounds__(256) void k_scanA(
    const int* __restrict__ deg, int* __restrict__ rowp,
    int* __restrict__ partials, int n){
  __shared__ int ws[4];
  int tid = threadIdx.x, lane = tid & 63, wid = tid >> 6;
  int i = blockIdx.x * 256 + tid;
  int v = (i < n) ? deg[i] : 0;
  int s = v;
  #pragma unroll
  for (int off = 1; off < 64; off <<= 1){ int u = __shfl_up(s, off); if (lane >= off) s += u; }
  if (lane == 63) ws[wid] = s;
  __syncthreads();
  if (tid < 4){
    int u = ws[tid];
    #pragma unroll
    for (int off = 1; off < 4; off <<= 1){ int q = __shfl_up(u, off); if (tid >= off) u += q; }
    ws[tid] = u;
  }
  __syncthreads();
  int woff = wid ? ws[wid - 1] : 0;
  if (i < n) rowp[i] = woff + s - v;   // block-local exclusive prefix
  if (tid == 255) partials[blockIdx.x] = ws[3];
}

// K3b: exclusive scan of block totals (in place) + grand total -> rowp[n]
__global__ __launch_bounds__(256) void k_scanB(
    int* __restrict__ partials, int* __restrict__ rowp, int nb, int n){
  __shared__ int ws[4];
  int tid = threadIdx.x, lane = tid & 63, wid = tid >> 6;
  int running = 0;
  for (int base = 0; base < nb; base += 256){
    int i = base + tid;
    int v = (i < nb) ? partials[i] : 0;
    int s = v;
    #pragma unroll
    for (int off = 1; off < 64; off <<= 1){ int u = __shfl_up(s, off); if (lane >= off) s += u; }
    if (lane == 63) ws[wid] = s;
    __syncthreads();
    if (tid < 4){
      int u = ws[tid];
      #pragma unroll
      for (int off = 1; off < 4; off <<= 1){ int q = __shfl_up(u, off); if (tid >= off) u += q; }
      ws[tid] = u;
    }
    __syncthreads();
    int woff = wid ? ws[wid - 1] : 0;
    if (i < nb) partials[i] = running + woff + s - v;
    running += ws[3];
    __syncthreads();
  }
  if (tid == 0) rowp[n] = running;
}

// K4: scatter (src, eattr) into CSR order keyed by dst (block offset folded in)
__global__ __launch_bounds__(256) void k_scatter(
    const int* __restrict__ srcI, const int* __restrict__ dstI,
    const float* __restrict__ eattr, const int* __restrict__ rowp,
    const int* __restrict__ partials, int* __restrict__ fill,
    int2* __restrict__ sortedSE, int E){
  int e = blockIdx.x * blockDim.x + threadIdx.x;
  if (e >= E) return;
  int t = dstI[e];
  int pos = rowp[t] + partials[t >> 8] + atomicAdd(&fill[t], 1);
  sortedSE[pos] = make_int2(srcI[e], __float_as_int(eattr[e]));
}

// K5: fused attention per dst row — one wave per node, 16 lanes per edge,
// 4 edges in flight; bf16 gathers (3 uint per row per lane); online softmax.
__global__ __launch_bounds__(256) void k_attn(
    const unsigned short* __restrict__ x2b, const float* __restrict__ x3,
    const unsigned short* __restrict__ x4b, const float* __restrict__ p5,
    const float* __restrict__ pb, const int2* __restrict__ sortedSE,
    const int* __restrict__ rowp, const int* __restrict__ partials,
    float* __restrict__ node_acc, int n){
  int t = blockIdx.x * 4 + (threadIdx.x >> 6);
  int lane = threadIdx.x & 63;
  if (t >= n) return;
  int beg = rowp[t] + partials[t >> 8];
  int end = (t + 1 < n) ? (rowp[t + 1] + partials[(t + 1) >> 8]) : rowp[n];
  if (beg == end) return;
  int j = lane & 15;

  const float2* r3 = (const float2*)(x3 + (size_t)t * D);
  float2 v0 = r3[j], v1 = r3[j + 16], v2 = r3[j + 32];
  float p5t = p5[t], pbt = pb[t];

  float m = -INFINITY, dsum = 0.0f;
  float a0 = 0, a1 = 0, a2 = 0, a3 = 0, a4 = 0, a5 = 0;

  for (int c = beg; c < end; c += 4){
    int g = lane >> 4;
    int ei = c + g;
    bool act = ei < end;
    int2 se = sortedSE[act ? ei : end - 1];
    const unsigned* r4 = (const unsigned*)(x4b + (size_t)se.x * D);
    unsigned u0 = r4[j], u1 = r4[j + 16], u2 = r4[j + 32];
    float s = v0.x * bflo(u0) + v0.y * bfhi(u0)
            + v1.x * bflo(u1) + v1.y * bfhi(u1)
            + v2.x * bflo(u2) + v2.y * bfhi(u2);
    s += __shfl_xor(s, 1); s += __shfl_xor(s, 2);
    s += __shfl_xor(s, 4); s += __shfl_xor(s, 8);
    float sc = act ? (s + __int_as_float(se.y) * p5t + pbt) * RSQ : -INFINITY;
    float mc = fmaxf(sc, __shfl_xor(sc, 16));
    mc = fmaxf(mc, __shfl_xor(mc, 32));
    if (mc > m){
      float r = __expf(m - mc);
      dsum *= r; a0 *= r; a1 *= r; a2 *= r; a3 *= r; a4 *= r; a5 *= r;
      m = mc;
    }
    float w = __expf(sc - m);
    dsum += w;
    const unsigned* r2 = (const unsigned*)(x2b + (size_t)se.x * D);
    unsigned q0 = r2[j], q1 = r2[j + 16], q2 = r2[j + 32];
    a0 += w * bflo(q0); a1 += w * bfhi(q0);
    a2 += w * bflo(q1); a3 += w * bfhi(q1);
    a4 += w * bflo(q2); a5 += w * bfhi(q2);
  }
  a0 += __shfl_xor(a0, 16); a0 += __shfl_xor(a0, 32);
  a1 += __shfl_xor(a1, 16); a1 += __shfl_xor(a1, 32);
  a2 += __shfl_xor(a2, 16); a2 += __shfl_xor(a2, 32);
  a3 += __shfl_xor(a3, 16); a3 += __shfl_xor(a3, 32);
  a4 += __shfl_xor(a4, 16); a4 += __shfl_xor(a4, 32);
  a5 += __shfl_xor(a5, 16); a5 += __shfl_xor(a5, 32);
  dsum += __shfl_xor(dsum, 16); dsum += __shfl_xor(dsum, 32);
  float inv = 1.0f / (dsum + 1e-16f);
  if (lane < 16){
    size_t o = (size_t)t * D + 2 * j;   // elems 2j,2j+1 / +32 / +64
    node_acc[o]      += a0 * inv;
    node_acc[o + 1]  += a1 * inv;
    node_acc[o + 32] += a2 * inv;
    node_acc[o + 33] += a3 * inv;
    node_acc[o + 64] += a4 * inv;
    node_acc[o + 65] += a5 * inv;
  }
}

// K6: per-graph partial sums (batch is sorted; binary-search boundaries)
__global__ __launch_bounds__(96) void k_pool(
    const float* __restrict__ node_out, const int* __restrict__ batch,
    float* __restrict__ sums, int n){
  int g = blockIdx.x;
  int chunk = blockIdx.y, nch = gridDim.y;
  int lo = lbound(batch, n, g);
  int hi = lbound(batch, n, g + 1);
  int cnt = hi - lo;
  if (cnt <= 0) return;
  int per = (cnt + nch - 1) / nch;
  int b = lo + chunk * per;
  int e = min(b + per, hi);
  if (b >= e) return;
  int d = threadIdx.x;
  float s = 0.0f;
  for (int r = b; r < e; ++r) s += node_out[(size_t)r * D + d];
  atomicAdd(&sums[g * D + d], s);
}

// K7: divide by counts
__global__ __launch_bounds__(256) void k_final(
    const float* __restrict__ sums, const int* __restrict__ batch,
    float* __restrict__ out, int n, int total){
  int i = blockIdx.x * blockDim.x + threadIdx.x;
  if (i >= total) return;
  int g = i / D;
  int lo = lbound(batch, n, g);
  int hi = lbound(batch, n, g + 1);
  float c = (float)((hi - lo) > 1 ? (hi - lo) : 1);
  out[i] = sums[i] / c;
}

extern "C" void kernel_launch(void* const* d_in, const int* in_sizes, int n_in,
                              void* d_out, int out_size, void* d_ws, size_t ws_size,
                              hipStream_t stream){
  const float* x     = (const float*)d_in[0];
  const int*   eidx  = (const int*)d_in[1];
  const float* eattr = (const float*)d_in[2];
  const int*   batch = (const int*)d_in[3];
  const float* w1 = (const float*)d_in[4];
  const float* b1 = (const float*)d_in[5];
  const float* w2 = (const float*)d_in[6];
  const float* b2 = (const float*)d_in[7];
  const float* w3 = (const float*)d_in[8];
  const float* b3 = (const float*)d_in[9];
  const float* w4 = (const float*)d_in[10];
  const float* b4 = (const float*)d_in[11];
  const float* w5 = (const float*)d_in[12];
  const float* b5 = (const float*)d_in[13];
  float* out = (float*)d_out;

  const int N = in_sizes[0] / D;
  const int E = in_sizes[2];
  const int* srcI = eidx;
  const int* dstI = eidx + E;
  const int NB = (N + 255) / 256;

  char* base = (char*)d_ws;
  size_t off = 0;
  auto alloc = [&](size_t bytes) -> char* {
    char* p = base + off;
    off = (off + bytes + 255) & ~(size_t)255;
    return p;
  };
  char* zbase = base;
  int*   deg  = (int*)alloc((size_t)N * 4);
  int*   fill = (int*)alloc((size_t)N * 4);
  float* sums = (float*)alloc((size_t)out_size * 4);
  size_t zbytes = off;
  float* node_acc = (float*)alloc((size_t)N * D * 4);
  unsigned short* x2v = (unsigned short*)alloc((size_t)N * D * 2);
  float* x3v      = (float*)alloc((size_t)N * D * 4);
  unsigned short* x4v = (unsigned short*)alloc((size_t)N * D * 2);
  float* p5       = (float*)alloc((size_t)N * 4);
  float* pb       = (float*)alloc((size_t)N * 4);
  int*   rowp     = (int*)alloc((size_t)(N + 1) * 4);
  int*   partials = (int*)alloc((size_t)(NB + 1) * 4);
  int2*  sortedSE = (int2*)alloc((size_t)E * 8);
  unsigned short* wt_h = (unsigned short*)alloc((size_t)4 * D * D * 2);
  unsigned short* wt_l = (unsigned short*)alloc((size_t)4 * D * D * 2);
  (void)ws_size; (void)n_in;

  hipMemsetAsync(zbase, 0, zbytes, stream);

  k_wprep<<<dim3((4 * D * D + 255) / 256), dim3(256), 0, stream>>>(
      w1, w2, w3, w4, wt_h, wt_l);
  k_transform_mfma<<<dim3((N + 15) / 16), dim3(256), 0, stream>>>(
      x, wt_h, wt_l, b1, b2, b3, b4, w5, b5,
      node_acc, x2v, x3v, x4v, p5, pb, N);
  k_deg<<<dim3((E + 255) / 256), dim3(256), 0, stream>>>(dstI, deg, E);
  k_scanA<<<dim3(NB), dim3(256), 0, stream>>>(deg, rowp, partials, N);
  k_scanB<<<dim3(1), dim3(256), 0, stream>>>(partials, rowp, NB, N);
  k_scatter<<<dim3((E + 255) / 256), dim3(256), 0, stream>>>(
      srcI, dstI, eattr, rowp, partials, fill, sortedSE, E);
  k_attn<<<dim3((N + 3) / 4), dim3(256), 0, stream>>>(
      x2v, x3v, x4v, p5, pb, sortedSE, rowp, partials, node_acc, N);
  k_pool<<<dim3(out_size / D, 32), dim3(D), 0, stream>>>(node_acc, batch, sums, N);
  k_final<<<dim3((out_size + 255) / 256), dim3(256), 0, stream>>>(
      sums, batch, out, N, out_size);
}